// Round 20
// baseline (153.703 us; speedup 1.0000x reference)
//
#include <hip/hip_runtime.h>

#define CC    48
#define HH    160
#define WWID  160
#define NPIX  25600
#define KK    8

typedef unsigned short u16;
typedef unsigned int u32;
typedef __attribute__((ext_vector_type(8))) short bf16x8;
typedef __attribute__((ext_vector_type(4))) float f32x4;

__device__ __forceinline__ float bf2f(u16 u) {
    return __uint_as_float(((unsigned int)u) << 16);
}
__device__ __forceinline__ u16 f2bf(float f) {
    unsigned int x = __float_as_uint(f);
    return (u16)((x + 0x7FFFu + ((x >> 16) & 1u)) >> 16);
}

// ws float-offset layout — non-aliased
#define OFF_B0    0        // 48
#define OFF_BK    48       // 12
#define OFF_WKT   60       // 576     wkt[c*12+r] = Wk[r][c]
#define OFF_WBH   636      // u16[256*64]: pixvt combined weight bf16-hi
#define OFF_WBL   8828     // u16[256*64]: bf16-lo
#define OFF_WLH   17020    // u16[48*192]: WL' bf16-hi
#define OFF_WLL   21628    // u16[48*192]: WL' bf16-lo
#define OFF_SQP   26236    // 25600
#define OFF_W0V   51836    // float[25600*48]
#define OFF_VTB   1280636  // u16[25600*192]
#define OFF_HHT   3738236  // u16[25600*64]
#define OFF_HLT   4557436  // u16[25600*64]
#define OFF_PARTK 5376636  // u32[8][8][NPIX] -> ends 7015036 (26.8 MB)

__global__ void prep_kernel(const float* W0, const float* b0, const float* WL,
                            const float* WR, const float* Wk, const float* bk,
                            float* ws) {
    float* b0f = ws + OFF_B0;
    float* bkf = ws + OFF_BK;
    float* wkt = ws + OFF_WKT;
    u16*   wbh = (u16*)(ws + OFF_WBH);
    u16*   wbl = (u16*)(ws + OFF_WBL);
    u16*   wlh = (u16*)(ws + OFF_WLH);
    u16*   wll = (u16*)(ws + OFF_WLL);
    int t = blockIdx.x * 256 + threadIdx.x;
    int stride = gridDim.x * 256;
    for (int i = t; i < 16384; i += stride) {
        int col = i >> 6, k = i & 63;
        float v = 0.f;
        if (k < 48) {
            if (col < 192)      v = WR[(4*k + (col & 3))*48 + (col >> 2)];
            else if (col < 240) v = W0[(col - 192)*48 + k];
        }
        u16 hi = f2bf(v);
        wbh[i] = hi;
        wbl[i] = f2bf(v - bf2f(hi));
    }
    for (int i = t; i < 9216; i += stride) {
        int o = i / 192, k = i % 192;
        float v = WL[(4*o + (k & 3))*48 + (k >> 2)];
        u16 hi = f2bf(v);
        wlh[i] = hi;
        wll[i] = f2bf(v - bf2f(hi));
    }
    for (int i = t; i < 576; i += stride) { int c = i / 12, r = i % 12; wkt[i] = Wk[r*48 + c]; }
    for (int i = t; i < 48; i += stride) { b0f[i] = b0[i]; }
    for (int i = t; i < 12; i += stride) { bkf[i] = bk[i]; }
}

// per-pixel: sq + bf16 hi/lo split rows; 2 threads per pixel (adjacent lanes)
__global__ __launch_bounds__(256) void split_kernel(const float* h, float* sqp,
                                                    u16* hht, u16* hlt) {
    int tid = threadIdx.x;
    int p = blockIdx.x * 128 + (tid >> 1);
    int half = tid & 1;
    float sq = 0.f;
    u16 hh[24], hl[24];
    #pragma unroll
    for (int i = 0; i < 24; i++) {
        int c = half*24 + i;
        float v = h[c*NPIX + p];
        sq = fmaf(v, v, sq);
        u16 hi = f2bf(v);
        hh[i] = hi;
        hl[i] = f2bf(v - bf2f(hi));
    }
    sq += __shfl_xor(sq, 1, 64);
    if (half == 0) sqp[p] = sq;
    uint4* dh = (uint4*)&hht[(long)p*64 + half*24];
    uint4* dl = (uint4*)&hlt[(long)p*64 + half*24];
    const uint4* s1 = (const uint4*)hh;
    const uint4* s2 = (const uint4*)hl;
    dh[0] = s1[0]; dh[1] = s1[1]; dh[2] = s1[2];
    dl[0] = s2[0]; dl[1] = s2[1]; dl[2] = s2[2];
    if (half) {
        uint4 z = make_uint4(0, 0, 0, 0);
        uint4* zh = (uint4*)&hht[(long)p*64 + 48];
        uint4* zl = (uint4*)&hlt[(long)p*64 + 48];
        zh[0] = z; zh[1] = z;
        zl[0] = z; zl[1] = z;
    }
}

// ---- pixvt via MFMA: per block 64 px x 256 weight-cols (192 VT bf16 + 48 W0V f32) ----
__global__ __launch_bounds__(512) void pixvt_mfma(const u16* hht, const u16* hlt,
                                                  const float* ws, float* w0v, u16* vtb) {
    __shared__ __align__(16) char smem[38912];
    u16*   a_hi = (u16*)smem;
    u16*   a_lo = (u16*)(smem + 8192);
    u16*   vt_s = (u16*)smem;
    float* w0_s = (float*)(smem + 25600);

    const u16* wbh = (const u16*)(ws + OFF_WBH);
    const u16* wbl = (const u16*)(ws + OFF_WBL);

    int tid = threadIdx.x;
    int pbase = blockIdx.x * 64;

    {
        int blk = tid >> 6, row = tid & 63;
        int swz = (blk ^ (row & 7)) * 8;
        *(uint4*)&a_hi[row*64 + swz] = *(const uint4*)&hht[(long)(pbase + row)*64 + blk*8];
        *(uint4*)&a_lo[row*64 + swz] = *(const uint4*)&hlt[(long)(pbase + row)*64 + blk*8];
    }
    __syncthreads();

    int w = tid >> 6, lane = tid & 63;
    int lm = lane & 15, lg = lane >> 4;
    int c2a = 2*w, c2b = 2*w + 1;

    f32x4 acc0[4], acc1[4];
    #pragma unroll
    for (int t = 0; t < 4; t++) { acc0[t] = (f32x4){0.f,0.f,0.f,0.f}; acc1[t] = (f32x4){0.f,0.f,0.f,0.f}; }

    #pragma unroll
    for (int s = 0; s < 2; s++) {
        int lblk = 4*s + lg;
        int aswz = (lblk ^ (lm & 7)) * 8;
        bf16x8 ah0 = *(const bf16x8*)&a_hi[( 0 + lm)*64 + aswz];
        bf16x8 ah1 = *(const bf16x8*)&a_hi[(16 + lm)*64 + aswz];
        bf16x8 ah2 = *(const bf16x8*)&a_hi[(32 + lm)*64 + aswz];
        bf16x8 ah3 = *(const bf16x8*)&a_hi[(48 + lm)*64 + aswz];
        bf16x8 al0 = *(const bf16x8*)&a_lo[( 0 + lm)*64 + aswz];
        bf16x8 al1 = *(const bf16x8*)&a_lo[(16 + lm)*64 + aswz];
        bf16x8 al2 = *(const bf16x8*)&a_lo[(32 + lm)*64 + aswz];
        bf16x8 al3 = *(const bf16x8*)&a_lo[(48 + lm)*64 + aswz];
        {
            int col = c2a*16 + lm;
            bf16x8 bh = *(const bf16x8*)&wbh[col*64 + lblk*8];
            bf16x8 bl = *(const bf16x8*)&wbl[col*64 + lblk*8];
            acc0[0] = __builtin_amdgcn_mfma_f32_16x16x32_bf16(ah0, bh, acc0[0], 0, 0, 0);
            acc0[0] = __builtin_amdgcn_mfma_f32_16x16x32_bf16(ah0, bl, acc0[0], 0, 0, 0);
            acc0[0] = __builtin_amdgcn_mfma_f32_16x16x32_bf16(al0, bh, acc0[0], 0, 0, 0);
            acc0[1] = __builtin_amdgcn_mfma_f32_16x16x32_bf16(ah1, bh, acc0[1], 0, 0, 0);
            acc0[1] = __builtin_amdgcn_mfma_f32_16x16x32_bf16(ah1, bl, acc0[1], 0, 0, 0);
            acc0[1] = __builtin_amdgcn_mfma_f32_16x16x32_bf16(al1, bh, acc0[1], 0, 0, 0);
            acc0[2] = __builtin_amdgcn_mfma_f32_16x16x32_bf16(ah2, bh, acc0[2], 0, 0, 0);
            acc0[2] = __builtin_amdgcn_mfma_f32_16x16x32_bf16(ah2, bl, acc0[2], 0, 0, 0);
            acc0[2] = __builtin_amdgcn_mfma_f32_16x16x32_bf16(al2, bh, acc0[2], 0, 0, 0);
            acc0[3] = __builtin_amdgcn_mfma_f32_16x16x32_bf16(ah3, bh, acc0[3], 0, 0, 0);
            acc0[3] = __builtin_amdgcn_mfma_f32_16x16x32_bf16(ah3, bl, acc0[3], 0, 0, 0);
            acc0[3] = __builtin_amdgcn_mfma_f32_16x16x32_bf16(al3, bh, acc0[3], 0, 0, 0);
        }
        if (c2b < 15) {
            int col = c2b*16 + lm;
            bf16x8 bh = *(const bf16x8*)&wbh[col*64 + lblk*8];
            bf16x8 bl = *(const bf16x8*)&wbl[col*64 + lblk*8];
            acc1[0] = __builtin_amdgcn_mfma_f32_16x16x32_bf16(ah0, bh, acc1[0], 0, 0, 0);
            acc1[0] = __builtin_amdgcn_mfma_f32_16x16x32_bf16(ah0, bl, acc1[0], 0, 0, 0);
            acc1[0] = __builtin_amdgcn_mfma_f32_16x16x32_bf16(al0, bh, acc1[0], 0, 0, 0);
            acc1[1] = __builtin_amdgcn_mfma_f32_16x16x32_bf16(ah1, bh, acc1[1], 0, 0, 0);
            acc1[1] = __builtin_amdgcn_mfma_f32_16x16x32_bf16(ah1, bl, acc1[1], 0, 0, 0);
            acc1[1] = __builtin_amdgcn_mfma_f32_16x16x32_bf16(al1, bh, acc1[1], 0, 0, 0);
            acc1[2] = __builtin_amdgcn_mfma_f32_16x16x32_bf16(ah2, bh, acc1[2], 0, 0, 0);
            acc1[2] = __builtin_amdgcn_mfma_f32_16x16x32_bf16(ah2, bl, acc1[2], 0, 0, 0);
            acc1[2] = __builtin_amdgcn_mfma_f32_16x16x32_bf16(al2, bh, acc1[2], 0, 0, 0);
            acc1[3] = __builtin_amdgcn_mfma_f32_16x16x32_bf16(ah3, bh, acc1[3], 0, 0, 0);
            acc1[3] = __builtin_amdgcn_mfma_f32_16x16x32_bf16(ah3, bl, acc1[3], 0, 0, 0);
            acc1[3] = __builtin_amdgcn_mfma_f32_16x16x32_bf16(al3, bh, acc1[3], 0, 0, 0);
        }
    }
    __syncthreads();

    {
        int col = c2a*16 + lm;
        if (c2a < 12) {
            #pragma unroll
            for (int t = 0; t < 4; t++)
                #pragma unroll
                for (int r = 0; r < 4; r++)
                    vt_s[(t*16 + lg*4 + r)*200 + col] = f2bf(acc0[t][r]);
        } else {
            int o = col - 192;
            #pragma unroll
            for (int t = 0; t < 4; t++)
                #pragma unroll
                for (int r = 0; r < 4; r++)
                    w0_s[(t*16 + lg*4 + r)*52 + o] = acc0[t][r];
        }
    }
    if (c2b < 15) {
        int col = c2b*16 + lm;
        if (c2b < 12) {
            #pragma unroll
            for (int t = 0; t < 4; t++)
                #pragma unroll
                for (int r = 0; r < 4; r++)
                    vt_s[(t*16 + lg*4 + r)*200 + col] = f2bf(acc1[t][r]);
        } else {
            int o = col - 192;
            #pragma unroll
            for (int t = 0; t < 4; t++)
                #pragma unroll
                for (int r = 0; r < 4; r++)
                    w0_s[(t*16 + lg*4 + r)*52 + o] = acc1[t][r];
        }
    }
    __syncthreads();

    {
        int px = tid >> 3, c8 = tid & 7;
        #pragma unroll
        for (int j = 0; j < 3; j++) {
            int ch = c8 + 8*j;
            uint4 v = *(const uint4*)&vt_s[px*200 + ch*8];
            *(uint4*)&vtb[(long)(pbase + px)*192 + ch*8] = v;
        }
        float* dst = w0v + (long)(pbase + px)*48 + c8*6;
        const float* src = w0_s + px*52 + c8*6;
        #pragma unroll
        for (int k = 0; k < 3; k++) {
            float2 v2 = *(const float2*)&src[k*2];
            *(float2*)&dst[k*2] = v2;
        }
    }
}

// ---- topk stage 1 (MFMA Gram, packed-key bubble selection, XCD-swizzled) ----
__global__ __launch_bounds__(512, 8) void topk_mfma(const u16* hht, const u16* hlt,
                                                    const float* sqp, u32* partk) {
    __shared__ u16 ca_hi[128*64];
    __shared__ u16 ca_lo[128*64];
    __shared__ float sq_s[128];

    int tid = threadIdx.x;
    int b = (blockIdx.x & 7) * 200 + (blockIdx.x >> 3);
    int chunk = b & 7, pg = (b >> 3) & 7, win = b >> 6;
    int wi = win / 5, wj = win % 5;
    int base = wi*32*WWID + wj*32;

    #pragma unroll
    for (int r = 0; r < 2; r++) {
        int task = r*512 + tid;
        int blk = task >> 7, row = task & 127;
        int swz = (blk ^ (row & 7)) * 8;
        int ml = chunk*128 + row;
        long gp = base + (ml>>5)*WWID + (ml&31);
        *(uint4*)&ca_hi[row*64 + swz] = *(const uint4*)&hht[gp*64 + blk*8];
        *(uint4*)&ca_lo[row*64 + swz] = *(const uint4*)&hlt[gp*64 + blk*8];
    }
    if (tid < 128) {
        int ml = chunk*128 + tid;
        sq_s[tid] = sqp[base + (ml>>5)*WWID + (ml&31)];
    }
    __syncthreads();

    int w = tid >> 6, lane = tid & 63;
    int lm = lane & 15, lg = lane >> 4;

    int nl = pg*128 + w*16 + lm;
    long gpx = base + (nl>>5)*WWID + (nl&31);

    f32x4 acc[8];
    #pragma unroll
    for (int t = 0; t < 8; t++) acc[t] = (f32x4){0.f, 0.f, 0.f, 0.f};

    #pragma unroll
    for (int s = 0; s < 2; s++) {
        int lblk = 4*s + lg;
        int ko = lblk * 8;
        bf16x8 bh = *(const bf16x8*)&hht[gpx*64 + ko];
        bf16x8 bl = *(const bf16x8*)&hlt[gpx*64 + ko];
        #pragma unroll
        for (int t = 0; t < 8; t++) {
            int aoff = (t*16 + lm)*64 + (lblk ^ (lm & 7))*8;
            bf16x8 ah = *(const bf16x8*)&ca_hi[aoff];
            bf16x8 al = *(const bf16x8*)&ca_lo[aoff];
            acc[t] = __builtin_amdgcn_mfma_f32_16x16x32_bf16(ah, bh, acc[t], 0, 0, 0);
            acc[t] = __builtin_amdgcn_mfma_f32_16x16x32_bf16(ah, bl, acc[t], 0, 0, 0);
            acc[t] = __builtin_amdgcn_mfma_f32_16x16x32_bf16(al, bh, acc[t], 0, 0, 0);
        }
    }

    int rn = nl >> 5, cn = nl & 31;
    int rowok[8], colok[8];
    #pragma unroll
    for (int t = 0; t < 8; t++) {
        int rm = chunk*4 + (t >> 1);
        int dr = rn - rm; dr = dr < 0 ? -dr : dr;
        rowok[t] = (dr <= 1);
    }
    #pragma unroll
    for (int j = 0; j < 8; j++) {
        int cm = (j >> 2)*16 + lg*4 + (j & 3);
        int dc = cn - cm; dc = dc < 0 ? -dc : dc;
        colok[j] = (dc <= 1);
    }

    u32 k8[8];
    #pragma unroll
    for (int s = 0; s < 8; s++) k8[s] = 0xFFFFFFFFu;

    #pragma unroll
    for (int t = 0; t < 8; t++) {
        #pragma unroll
        for (int r = 0; r < 4; r++) {
            int cl = t*16 + lg*4 + r;
            int ml = chunk*128 + cl;
            float d = fmaf(-2.0f, acc[t][r], sq_s[cl]);
            u32 u = __float_as_uint(d);
            u32 key = u ^ (0x80000000u | (u32)((int)u >> 31));
            key = (key & 0xFFFFFC00u) | (u32)ml;
            bool bad = rowok[t] && colok[(t & 1)*4 + r];
            key = bad ? 0xFFFFFFFFu : key;
            #pragma unroll
            for (int s = 0; s < 8; s++) {
                u32 lo = min(k8[s], key);
                u32 hi = max(k8[s], key);
                k8[s] = lo; key = hi;
            }
        }
    }

    #pragma unroll
    for (int st = 0; st < 2; st++) {
        int mk = (st == 0) ? 16 : 32;
        u32 o[8];
        #pragma unroll
        for (int s = 0; s < 8; s++) o[s] = (u32)__shfl_xor((int)k8[s], mk, 64);
        u32 c0 = min(k8[0], o[7]);
        u32 c1 = min(k8[1], o[6]);
        u32 c2 = min(k8[2], o[5]);
        u32 c3 = min(k8[3], o[4]);
        u32 c4 = min(k8[4], o[3]);
        u32 c5 = min(k8[5], o[2]);
        u32 c6 = min(k8[6], o[1]);
        u32 c7 = min(k8[7], o[0]);
        u32 a, bb;
        a = min(c0,c4); bb = max(c0,c4); c0 = a; c4 = bb;
        a = min(c1,c5); bb = max(c1,c5); c1 = a; c5 = bb;
        a = min(c2,c6); bb = max(c2,c6); c2 = a; c6 = bb;
        a = min(c3,c7); bb = max(c3,c7); c3 = a; c7 = bb;
        a = min(c0,c2); bb = max(c0,c2); c0 = a; c2 = bb;
        a = min(c1,c3); bb = max(c1,c3); c1 = a; c3 = bb;
        a = min(c4,c6); bb = max(c4,c6); c4 = a; c6 = bb;
        a = min(c5,c7); bb = max(c5,c7); c5 = a; c7 = bb;
        a = min(c0,c1); bb = max(c0,c1); c0 = a; c1 = bb;
        a = min(c2,c3); bb = max(c2,c3); c2 = a; c3 = bb;
        a = min(c4,c5); bb = max(c4,c5); c4 = a; c5 = bb;
        a = min(c6,c7); bb = max(c6,c7); c6 = a; c7 = bb;
        k8[0]=c0; k8[1]=c1; k8[2]=c2; k8[3]=c3; k8[4]=c4; k8[5]=c5; k8[6]=c6; k8[7]=c7;
    }

    {
        int n = base + (nl >> 5)*WWID + (nl & 31);
        u32 v0, v1;
        if      (lg == 0) { v0 = k8[0]; v1 = k8[1]; }
        else if (lg == 1) { v0 = k8[2]; v1 = k8[3]; }
        else if (lg == 2) { v0 = k8[4]; v1 = k8[5]; }
        else              { v0 = k8[6]; v1 = k8[7]; }
        u32* pk = partk + (long)chunk*8*NPIX + (long)(2*lg)*NPIX + n;
        pk[0]    = v0;
        pk[NPIX] = v1;
    }
}

// ---- ecc fused: 2 lanes/edge (NO byte duplication) + Ubar LDS + in-kernel WL MFMA ----
__global__ __launch_bounds__(256) void ecc_kernel(const float* ws, const u32* partk,
                                                  const u16* vtb, float* outp) {
    const float* b0f = ws + OFF_B0;
    const float* bkf = ws + OFF_BK;
    const float* wkt = ws + OFF_WKT;
    const float* w0v = ws + OFF_W0V;
    const float* sqp = ws + OFF_SQP;
    const u16*   wlh = (const u16*)(ws + OFF_WLH);
    const u16*   wll = (const u16*)(ws + OFF_WLL);

    __shared__ u16 th_s[128][50];
    __shared__ __align__(16) u16 ub_s[16*200];

    int tid = threadIdx.x;
    int sb = (blockIdx.x & 7) * 200 + (blockIdx.x >> 3);
    int pix = tid >> 4;            // 0..15
    int lane16 = tid & 15;
    int ek = lane16 >> 1;          // edge 0..7
    int half = lane16 & 1;
    int lane = tid & 63;
    int erow = tid >> 1;           // block edge row = pix*8 + ek
    int n = sb * 16 + pix;

    // merge: even lanes load chunk ek's sorted list; odd lanes carry sentinels
    u32 k8[8];
    if (half == 0) {
        const u32* pk = partk + (long)ek*8*NPIX + n;
        #pragma unroll
        for (int s = 0; s < 8; s++) k8[s] = pk[(long)s*NPIX];
    } else {
        #pragma unroll
        for (int s = 0; s < 8; s++) k8[s] = 0xFFFFFFFFu;
    }
    #pragma unroll
    for (int st = 0; st < 3; st++) {
        int mk = 2 << st;          // masks 2,4,8: permute ek bits, keep half bit
        u32 o[8];
        #pragma unroll
        for (int s = 0; s < 8; s++) o[s] = (u32)__shfl_xor((int)k8[s], mk, 64);
        u32 c0 = min(k8[0], o[7]);
        u32 c1 = min(k8[1], o[6]);
        u32 c2 = min(k8[2], o[5]);
        u32 c3 = min(k8[3], o[4]);
        u32 c4 = min(k8[4], o[3]);
        u32 c5 = min(k8[5], o[2]);
        u32 c6 = min(k8[6], o[1]);
        u32 c7 = min(k8[7], o[0]);
        u32 a, bb;
        a = min(c0,c4); bb = max(c0,c4); c0 = a; c4 = bb;
        a = min(c1,c5); bb = max(c1,c5); c1 = a; c5 = bb;
        a = min(c2,c6); bb = max(c2,c6); c2 = a; c6 = bb;
        a = min(c3,c7); bb = max(c3,c7); c3 = a; c7 = bb;
        a = min(c0,c2); bb = max(c0,c2); c0 = a; c2 = bb;
        a = min(c1,c3); bb = max(c1,c3); c1 = a; c3 = bb;
        a = min(c4,c6); bb = max(c4,c6); c4 = a; c6 = bb;
        a = min(c5,c7); bb = max(c5,c7); c5 = a; c7 = bb;
        a = min(c0,c1); bb = max(c0,c1); c0 = a; c1 = bb;
        a = min(c2,c3); bb = max(c2,c3); c2 = a; c3 = bb;
        a = min(c4,c5); bb = max(c4,c5); c4 = a; c5 = bb;
        a = min(c6,c7); bb = max(c6,c7); c6 = a; c7 = bb;
        k8[0]=c0; k8[1]=c1; k8[2]=c2; k8[3]=c3; k8[4]=c4; k8[5]=c5; k8[6]=c6; k8[7]=c7;
    }
    // even lane ek holds sorted list; rank-ek mux, then broadcast to the pair
    u32 muxval;
    {
        int sc = ek;
        u32 m0 = (sc & 1) ? k8[1] : k8[0];
        u32 m1 = (sc & 1) ? k8[3] : k8[2];
        u32 m2 = (sc & 1) ? k8[5] : k8[4];
        u32 m3 = (sc & 2) ? ((sc & 1) ? k8[3] : k8[2]) : m0;   // placeholder (recomputed below)
        u32 n0 = (sc & 2) ? m1 : m0;
        u32 n1 = (sc & 2) ? ((sc & 1) ? k8[7] : k8[6]) : m2;
        // standard 3-level mux:
        u32 q0 = (sc & 1) ? k8[1] : k8[0];
        u32 q1 = (sc & 1) ? k8[3] : k8[2];
        u32 q2 = (sc & 1) ? k8[5] : k8[4];
        u32 q3 = (sc & 1) ? k8[7] : k8[6];
        u32 r0 = (sc & 2) ? q1 : q0;
        u32 r1 = (sc & 2) ? q3 : q2;
        muxval = (sc & 4) ? r1 : r0;
        (void)m3; (void)n0; (void)n1;
    }
    u32 key = (u32)__shfl((int)muxval, (lane & 48) + 2*ek, 64);
    int ml = (int)(key & 1023u);
    u32 uf = key & 0xFFFFFC00u;
    u32 uu = (uf & 0x80000000u) ? (uf ^ 0x80000000u) : ~uf;
    float d = __uint_as_float(uu);
    int y = n / WWID, x = n % WWID;
    int wy = (y >> 5) << 5, wx = (x >> 5) << 5;
    int m = (wy + (ml >> 5)) * WWID + (wx + (ml & 31));
    float gamma = expf(-(d + sqp[n]) * 0.1f);

    // vtb prefetch: each half loads ITS 12 uint4 (cp range [24h, 24h+24))
    const u16* vrow = vtb + (long)m * 192 + half*96;
    uint4 vv[6];
    #pragma unroll
    for (int jj = 0; jj < 6; jj++) vv[jj] = *(const uint4*)&vrow[jj*8];

    // theta: each half computes ITS 24 channels from its own w0v slice
    float th26[26];
    {
        const float4* wm4 = (const float4*)(w0v + (long)m * 48) + half*6;
        const float4* wn4 = (const float4*)(w0v + (long)n * 48) + half*6;
        #pragma unroll
        for (int i = 0; i < 6; i++) {
            float4 a = wm4[i];
            float4 b = wn4[i];
            int c0 = half*24 + 4*i;
            float x0 = a.x - b.x + b0f[c0+0];
            float x1 = a.y - b.y + b0f[c0+1];
            float x2 = a.z - b.z + b0f[c0+2];
            float x3 = a.w - b.w + b0f[c0+3];
            th26[4*i+0] = (x0 >= 0.f) ? x0 : 0.01f * x0;
            th26[4*i+1] = (x1 >= 0.f) ? x1 : 0.01f * x1;
            th26[4*i+2] = (x2 >= 0.f) ? x2 : 0.01f * x2;
            th26[4*i+3] = (x3 >= 0.f) ? x3 : 0.01f * x3;
        }
    }
    // boundary values from partner (exact fp32): half0 gets th[24],th[25]; half1 gets th[0],th[1]
    th26[24] = __shfl_xor(th26[0], 1, 64);
    th26[25] = __shfl_xor(th26[1], 1, 64);

    // stage this half's theta (bf16) to th_s
    #pragma unroll
    for (int i = 0; i < 12; i++) {
        ushort2 pr;
        pr.x = f2bf(th26[2*i]);
        pr.y = f2bf(th26[2*i+1]);
        *(ushort2*)&th_s[erow][half*24 + 2*i] = pr;
    }

    // kappa: half-sum + pair combine
    float kap[12];
    #pragma unroll
    for (int r = 0; r < 12; r++) kap[r] = half ? 0.f : bkf[r];
    #pragma unroll
    for (int i = 0; i < 24; i++) {
        int c = half*24 + i;
        float t = th26[i];
        const float* wkc = wkt + c*12;
        #pragma unroll
        for (int r = 0; r < 12; r++) kap[r] = fmaf(wkc[r], t, kap[r]);
    }
    #pragma unroll
    for (int r = 0; r < 12; r++) kap[r] += __shfl_xor(kap[r], 1, 64);

    // sr: half-sum over local cp l = 0..23 (global cp = 24h + l) + pair combine
    float sr[12];
    #pragma unroll
    for (int r = 0; r < 12; r++) sr[r] = 0.f;
    #pragma unroll
    for (int j = 0; j < 6; j++) {
        uint4 v4 = vv[j];
        #pragma unroll
        for (int hf = 0; hf < 2; hf++) {
            int l = 2*j + hf;
            u32 w0_ = hf ? v4.z : v4.x;
            u32 w1_ = hf ? v4.w : v4.y;
            float vx = bf2f((u16)(w0_ & 0xffff));
            float vy = bf2f((u16)(w0_ >> 16));
            float vz = bf2f((u16)(w1_ & 0xffff));
            float vw = bf2f((u16)(w1_ >> 16));
            float t0 = th26[l], t1 = th26[l+1], t2 = th26[l+2];
            sr[0] = fmaf(t0, vx, sr[0]); sr[1]  = fmaf(t1, vx, sr[1]);  sr[2]  = fmaf(t2, vx, sr[2]);
            sr[3] = fmaf(t0, vy, sr[3]); sr[4]  = fmaf(t1, vy, sr[4]);  sr[5]  = fmaf(t2, vy, sr[5]);
            sr[6] = fmaf(t0, vz, sr[6]); sr[7]  = fmaf(t1, vz, sr[7]);  sr[8]  = fmaf(t2, vz, sr[8]);
            sr[9] = fmaf(t0, vw, sr[9]); sr[10] = fmaf(t1, vw, sr[10]); sr[11] = fmaf(t2, vw, sr[11]);
        }
    }
    #pragma unroll
    for (int jj = 0; jj < 6; jj++) vv[jj] = *(const uint4*)&vrow[(6 + jj)*8];
    #pragma unroll
    for (int j = 0; j < 6; j++) {
        uint4 v4 = vv[j];
        #pragma unroll
        for (int hf = 0; hf < 2; hf++) {
            int l = 12 + 2*j + hf;
            u32 w0_ = hf ? v4.z : v4.x;
            u32 w1_ = hf ? v4.w : v4.y;
            float vx = bf2f((u16)(w0_ & 0xffff));
            float vy = bf2f((u16)(w0_ >> 16));
            float vz = bf2f((u16)(w1_ & 0xffff));
            float vw = bf2f((u16)(w1_ >> 16));
            float t0 = th26[l], t1 = th26[l+1], t2 = th26[l+2];
            sr[0] = fmaf(t0, vx, sr[0]); sr[1]  = fmaf(t1, vx, sr[1]);  sr[2]  = fmaf(t2, vx, sr[2]);
            sr[3] = fmaf(t0, vy, sr[3]); sr[4]  = fmaf(t1, vy, sr[4]);  sr[5]  = fmaf(t2, vy, sr[5]);
            sr[6] = fmaf(t0, vz, sr[6]); sr[7]  = fmaf(t1, vz, sr[7]);  sr[8]  = fmaf(t2, vz, sr[8]);
            sr[9] = fmaf(t0, vw, sr[9]); sr[10] = fmaf(t1, vw, sr[10]); sr[11] = fmaf(t2, vw, sr[11]);
        }
    }
    #pragma unroll
    for (int r = 0; r < 12; r++) sr[r] += __shfl_xor(sr[r], 1, 64);

    float tmp[12];
    #pragma unroll
    for (int r = 0; r < 12; r++) tmp[r] = kap[r] * sr[r];

    __syncthreads();

    // phase B: 16 lanes per pixel, 3 cps each
    float acc0[3], acc1[3], acc2[3], acc3[3];
    #pragma unroll
    for (int j = 0; j < 3; j++) { acc0[j] = 0.f; acc1[j] = 0.f; acc2[j] = 0.f; acc3[j] = 0.f; }
    #pragma unroll 1
    for (int e = 0; e < 8; e++) {
        int srcl = (lane & 48) + 2*e;
        int row  = pix*8 + e;
        float tm[12];
        #pragma unroll
        for (int r = 0; r < 12; r++) tm[r] = __shfl(tmp[r], srcl, 64);
        float ge = __shfl(gamma, srcl, 64);
        #pragma unroll
        for (int j = 0; j < 3; j++) {
            int cp = lane16 + 16*j;
            int i1 = (cp + 1 < 48) ? cp + 1 : cp - 47;
            int i2 = (cp + 2 < 48) ? cp + 2 : cp - 46;
            float t0 = bf2f(th_s[row][cp]);
            float t1 = bf2f(th_s[row][i1]);
            float t2 = bf2f(th_s[row][i2]);
            float u0 = tm[0]*t0 + tm[1]*t1 + tm[2]*t2;
            float u1 = tm[3]*t0 + tm[4]*t1 + tm[5]*t2;
            float u2 = tm[6]*t0 + tm[7]*t1 + tm[8]*t2;
            float u3 = tm[9]*t0 + tm[10]*t1 + tm[11]*t2;
            acc0[j] = fmaf(ge, u0, acc0[j]);
            acc1[j] = fmaf(ge, u1, acc1[j]);
            acc2[j] = fmaf(ge, u2, acc2[j]);
            acc3[j] = fmaf(ge, u3, acc3[j]);
        }
    }
    {
        u16* ub = &ub_s[pix*200];
        #pragma unroll
        for (int j = 0; j < 3; j++) {
            int cp = lane16 + 16*j;
            ushort4 st;
            st.x = f2bf(acc0[j]); st.y = f2bf(acc1[j]);
            st.z = f2bf(acc2[j]); st.w = f2bf(acc3[j]);
            *(ushort4*)&ub[cp*4] = st;
        }
    }
    __syncthreads();

    // WL MFMA: 3 waves x 1 col-tile each; out[48 x 16]
    {
        int w2 = tid >> 6;
        if (w2 < 3) {
            int lm = lane & 15, lg = lane >> 4;
            int nb = sb * 16;
            f32x4 a0 = (f32x4){0.f,0.f,0.f,0.f};
            #pragma unroll
            for (int ks = 0; ks < 6; ks++) {
                bf16x8 a = *(const bf16x8*)&ub_s[lm*200 + ks*32 + lg*8];
                bf16x8 bh = *(const bf16x8*)&wlh[(w2*16 + lm)*192 + ks*32 + lg*8];
                bf16x8 bl = *(const bf16x8*)&wll[(w2*16 + lm)*192 + ks*32 + lg*8];
                a0 = __builtin_amdgcn_mfma_f32_16x16x32_bf16(a, bh, a0, 0, 0, 0);
                a0 = __builtin_amdgcn_mfma_f32_16x16x32_bf16(a, bl, a0, 0, 0, 0);
            }
            #pragma unroll
            for (int r = 0; r < 4; r++) {
                int px = lg*4 + r;
                outp[(long)(w2*16 + lm)*NPIX + nb + px] = 0.0625f * a0[r];
            }
        }
    }
}

// ---- conv 3x3 (reflect pad), OCH=4/thread, XCD-chunked swizzle, adds 0.5*hL + bias ----
#define OCH 4
__global__ __launch_bounds__(320) void conv_kernel(const float* h, const float* wc,
                                                   const float* bias, float* outp) {
    int sb = (blockIdx.x & 7) * 120 + (blockIdx.x >> 3);
    int og = sb % 12;
    int yp = sb / 12;
    int t  = threadIdx.x;
    int ty = t / 160;
    int x  = t % 160;
    int y  = yp * 2 + ty;

    int idx9[9];
    #pragma unroll
    for (int dy = 0; dy < 3; dy++) {
        int yy = y + dy - 1;
        yy = yy < 0 ? -yy : (yy >= HH ? 2*HH - 2 - yy : yy);
        #pragma unroll
        for (int dx = 0; dx < 3; dx++) {
            int xx = x + dx - 1;
            xx = xx < 0 ? -xx : (xx >= WWID ? 2*WWID - 2 - xx : xx);
            idx9[dy*3 + dx] = yy * WWID + xx;
        }
    }

    float acc[OCH];
    #pragma unroll
    for (int oi = 0; oi < OCH; oi++) acc[oi] = 0.f;

    const float* wbase = wc + og * OCH * 432;
    for (int c = 0; c < 48; c++) {
        float v[9];
        #pragma unroll
        for (int k = 0; k < 9; k++) v[k] = h[c*NPIX + idx9[k]];
        #pragma unroll
        for (int oi = 0; oi < OCH; oi++) {
            const float* w9 = wbase + oi*432 + c*9;
            float a = acc[oi];
            a = fmaf(v[0], w9[0], a);
            a = fmaf(v[1], w9[1], a);
            a = fmaf(v[2], w9[2], a);
            a = fmaf(v[3], w9[3], a);
            a = fmaf(v[4], w9[4], a);
            a = fmaf(v[5], w9[5], a);
            a = fmaf(v[6], w9[6], a);
            a = fmaf(v[7], w9[7], a);
            a = fmaf(v[8], w9[8], a);
            acc[oi] = a;
        }
    }

    int p = y * WWID + x;
    #pragma unroll
    for (int oi = 0; oi < OCH; oi++) {
        int o = og * OCH + oi;
        outp[o*NPIX + p] = outp[o*NPIX + p] + 0.5f * acc[oi] + bias[o];
    }
}

extern "C" void kernel_launch(void* const* d_in, const int* in_sizes, int n_in,
                              void* d_out, int out_size, void* d_ws, size_t ws_size,
                              hipStream_t stream) {
    const float* h    = (const float*)d_in[0];
    const float* W0   = (const float*)d_in[1];
    const float* b0   = (const float*)d_in[2];
    const float* WL   = (const float*)d_in[3];
    const float* WR   = (const float*)d_in[4];
    const float* Wk   = (const float*)d_in[5];
    const float* bk   = (const float*)d_in[6];
    const float* Wc   = (const float*)d_in[7];
    const float* bias = (const float*)d_in[8];

    float* ws     = (float*)d_ws;
    float* sqp    = ws + OFF_SQP;
    float* w0v    = ws + OFF_W0V;
    u16*   vtb    = (u16*)(ws + OFF_VTB);
    u16*   hht    = (u16*)(ws + OFF_HHT);
    u16*   hlt    = (u16*)(ws + OFF_HLT);
    u32*   partk  = (u32*)(ws + OFF_PARTK);
    float* outp   = (float*)d_out;

    prep_kernel<<<dim3(16), dim3(256), 0, stream>>>(W0, b0, WL, WR, Wk, bk, ws);
    split_kernel<<<dim3(200), dim3(256), 0, stream>>>(h, sqp, hht, hlt);
    topk_mfma<<<dim3(1600), dim3(512), 0, stream>>>(hht, hlt, sqp, partk);
    pixvt_mfma<<<dim3(400), dim3(512), 0, stream>>>(hht, hlt, ws, w0v, vtb);
    ecc_kernel<<<dim3(1600), dim3(256), 0, stream>>>(ws, partk, vtb, outp);
    conv_kernel<<<dim3(960), dim3(320), 0, stream>>>(h, Wc, bias, outp);
}

// Round 21
// 132.065 us; speedup vs baseline: 1.1638x; 1.1638x over previous
//
#include <hip/hip_runtime.h>

#define CC    48
#define HH    160
#define WWID  160
#define NPIX  25600
#define KK    8

typedef unsigned short u16;
typedef unsigned int u32;
typedef __attribute__((ext_vector_type(8))) short bf16x8;
typedef __attribute__((ext_vector_type(4))) float f32x4;

__device__ __forceinline__ float bf2f(u16 u) {
    return __uint_as_float(((unsigned int)u) << 16);
}
__device__ __forceinline__ u16 f2bf(float f) {
    unsigned int x = __float_as_uint(f);
    return (u16)((x + 0x7FFFu + ((x >> 16) & 1u)) >> 16);
}

// ws float-offset layout — non-aliased
#define OFF_B0    0        // 48
#define OFF_BK    48       // 12
#define OFF_WKT   60       // 576     wkt[c*12+r] = Wk[r][c]
#define OFF_WBH   636      // u16[256*64]: pixvt combined weight bf16-hi
#define OFF_WBL   8828     // u16[256*64]: bf16-lo
#define OFF_WLH   17020    // u16[48*192]: WL' bf16-hi
#define OFF_WLL   21628    // u16[48*192]: WL' bf16-lo
#define OFF_SQP   26236    // 25600
#define OFF_W0V   51836    // float[25600*48]
#define OFF_VTB   1280636  // u16[25600*192]
#define OFF_HHT   3738236  // u16[25600*64]
#define OFF_HLT   4557436  // u16[25600*64]
#define OFF_PARTK 5376636  // u32[8][8][NPIX] -> ends 7015036 (26.8 MB)

__global__ void prep_kernel(const float* W0, const float* b0, const float* WL,
                            const float* WR, const float* Wk, const float* bk,
                            float* ws) {
    float* b0f = ws + OFF_B0;
    float* bkf = ws + OFF_BK;
    float* wkt = ws + OFF_WKT;
    u16*   wbh = (u16*)(ws + OFF_WBH);
    u16*   wbl = (u16*)(ws + OFF_WBL);
    u16*   wlh = (u16*)(ws + OFF_WLH);
    u16*   wll = (u16*)(ws + OFF_WLL);
    int t = blockIdx.x * 256 + threadIdx.x;
    int stride = gridDim.x * 256;
    for (int i = t; i < 16384; i += stride) {
        int col = i >> 6, k = i & 63;
        float v = 0.f;
        if (k < 48) {
            if (col < 192)      v = WR[(4*k + (col & 3))*48 + (col >> 2)];
            else if (col < 240) v = W0[(col - 192)*48 + k];
        }
        u16 hi = f2bf(v);
        wbh[i] = hi;
        wbl[i] = f2bf(v - bf2f(hi));
    }
    for (int i = t; i < 9216; i += stride) {
        int o = i / 192, k = i % 192;
        float v = WL[(4*o + (k & 3))*48 + (k >> 2)];
        u16 hi = f2bf(v);
        wlh[i] = hi;
        wll[i] = f2bf(v - bf2f(hi));
    }
    for (int i = t; i < 576; i += stride) { int c = i / 12, r = i % 12; wkt[i] = Wk[r*48 + c]; }
    for (int i = t; i < 48; i += stride) { b0f[i] = b0[i]; }
    for (int i = t; i < 12; i += stride) { bkf[i] = bk[i]; }
}

// per-pixel: sq + bf16 hi/lo split rows; 2 threads per pixel (adjacent lanes)
__global__ __launch_bounds__(256) void split_kernel(const float* h, float* sqp,
                                                    u16* hht, u16* hlt) {
    int tid = threadIdx.x;
    int p = blockIdx.x * 128 + (tid >> 1);
    int half = tid & 1;
    float sq = 0.f;
    u16 hh[24], hl[24];
    #pragma unroll
    for (int i = 0; i < 24; i++) {
        int c = half*24 + i;
        float v = h[c*NPIX + p];
        sq = fmaf(v, v, sq);
        u16 hi = f2bf(v);
        hh[i] = hi;
        hl[i] = f2bf(v - bf2f(hi));
    }
    sq += __shfl_xor(sq, 1, 64);
    if (half == 0) sqp[p] = sq;
    uint4* dh = (uint4*)&hht[(long)p*64 + half*24];
    uint4* dl = (uint4*)&hlt[(long)p*64 + half*24];
    const uint4* s1 = (const uint4*)hh;
    const uint4* s2 = (const uint4*)hl;
    dh[0] = s1[0]; dh[1] = s1[1]; dh[2] = s1[2];
    dl[0] = s2[0]; dl[1] = s2[1]; dl[2] = s2[2];
    if (half) {
        uint4 z = make_uint4(0, 0, 0, 0);
        uint4* zh = (uint4*)&hht[(long)p*64 + 48];
        uint4* zl = (uint4*)&hlt[(long)p*64 + 48];
        zh[0] = z; zh[1] = z;
        zl[0] = z; zl[1] = z;
    }
}

// ---- pixvt via MFMA: per block 64 px x 256 weight-cols (192 VT bf16 + 48 W0V f32) ----
__global__ __launch_bounds__(512) void pixvt_mfma(const u16* hht, const u16* hlt,
                                                  const float* ws, float* w0v, u16* vtb) {
    __shared__ __align__(16) char smem[38912];
    u16*   a_hi = (u16*)smem;
    u16*   a_lo = (u16*)(smem + 8192);
    u16*   vt_s = (u16*)smem;
    float* w0_s = (float*)(smem + 25600);

    const u16* wbh = (const u16*)(ws + OFF_WBH);
    const u16* wbl = (const u16*)(ws + OFF_WBL);

    int tid = threadIdx.x;
    int pbase = blockIdx.x * 64;

    {
        int blk = tid >> 6, row = tid & 63;
        int swz = (blk ^ (row & 7)) * 8;
        *(uint4*)&a_hi[row*64 + swz] = *(const uint4*)&hht[(long)(pbase + row)*64 + blk*8];
        *(uint4*)&a_lo[row*64 + swz] = *(const uint4*)&hlt[(long)(pbase + row)*64 + blk*8];
    }
    __syncthreads();

    int w = tid >> 6, lane = tid & 63;
    int lm = lane & 15, lg = lane >> 4;
    int c2a = 2*w, c2b = 2*w + 1;

    f32x4 acc0[4], acc1[4];
    #pragma unroll
    for (int t = 0; t < 4; t++) { acc0[t] = (f32x4){0.f,0.f,0.f,0.f}; acc1[t] = (f32x4){0.f,0.f,0.f,0.f}; }

    #pragma unroll
    for (int s = 0; s < 2; s++) {
        int lblk = 4*s + lg;
        int aswz = (lblk ^ (lm & 7)) * 8;
        bf16x8 ah0 = *(const bf16x8*)&a_hi[( 0 + lm)*64 + aswz];
        bf16x8 ah1 = *(const bf16x8*)&a_hi[(16 + lm)*64 + aswz];
        bf16x8 ah2 = *(const bf16x8*)&a_hi[(32 + lm)*64 + aswz];
        bf16x8 ah3 = *(const bf16x8*)&a_hi[(48 + lm)*64 + aswz];
        bf16x8 al0 = *(const bf16x8*)&a_lo[( 0 + lm)*64 + aswz];
        bf16x8 al1 = *(const bf16x8*)&a_lo[(16 + lm)*64 + aswz];
        bf16x8 al2 = *(const bf16x8*)&a_lo[(32 + lm)*64 + aswz];
        bf16x8 al3 = *(const bf16x8*)&a_lo[(48 + lm)*64 + aswz];
        {
            int col = c2a*16 + lm;
            bf16x8 bh = *(const bf16x8*)&wbh[col*64 + lblk*8];
            bf16x8 bl = *(const bf16x8*)&wbl[col*64 + lblk*8];
            acc0[0] = __builtin_amdgcn_mfma_f32_16x16x32_bf16(ah0, bh, acc0[0], 0, 0, 0);
            acc0[0] = __builtin_amdgcn_mfma_f32_16x16x32_bf16(ah0, bl, acc0[0], 0, 0, 0);
            acc0[0] = __builtin_amdgcn_mfma_f32_16x16x32_bf16(al0, bh, acc0[0], 0, 0, 0);
            acc0[1] = __builtin_amdgcn_mfma_f32_16x16x32_bf16(ah1, bh, acc0[1], 0, 0, 0);
            acc0[1] = __builtin_amdgcn_mfma_f32_16x16x32_bf16(ah1, bl, acc0[1], 0, 0, 0);
            acc0[1] = __builtin_amdgcn_mfma_f32_16x16x32_bf16(al1, bh, acc0[1], 0, 0, 0);
            acc0[2] = __builtin_amdgcn_mfma_f32_16x16x32_bf16(ah2, bh, acc0[2], 0, 0, 0);
            acc0[2] = __builtin_amdgcn_mfma_f32_16x16x32_bf16(ah2, bl, acc0[2], 0, 0, 0);
            acc0[2] = __builtin_amdgcn_mfma_f32_16x16x32_bf16(al2, bh, acc0[2], 0, 0, 0);
            acc0[3] = __builtin_amdgcn_mfma_f32_16x16x32_bf16(ah3, bh, acc0[3], 0, 0, 0);
            acc0[3] = __builtin_amdgcn_mfma_f32_16x16x32_bf16(ah3, bl, acc0[3], 0, 0, 0);
            acc0[3] = __builtin_amdgcn_mfma_f32_16x16x32_bf16(al3, bh, acc0[3], 0, 0, 0);
        }
        if (c2b < 15) {
            int col = c2b*16 + lm;
            bf16x8 bh = *(const bf16x8*)&wbh[col*64 + lblk*8];
            bf16x8 bl = *(const bf16x8*)&wbl[col*64 + lblk*8];
            acc1[0] = __builtin_amdgcn_mfma_f32_16x16x32_bf16(ah0, bh, acc1[0], 0, 0, 0);
            acc1[0] = __builtin_amdgcn_mfma_f32_16x16x32_bf16(ah0, bl, acc1[0], 0, 0, 0);
            acc1[0] = __builtin_amdgcn_mfma_f32_16x16x32_bf16(al0, bh, acc1[0], 0, 0, 0);
            acc1[1] = __builtin_amdgcn_mfma_f32_16x16x32_bf16(ah1, bh, acc1[1], 0, 0, 0);
            acc1[1] = __builtin_amdgcn_mfma_f32_16x16x32_bf16(ah1, bl, acc1[1], 0, 0, 0);
            acc1[1] = __builtin_amdgcn_mfma_f32_16x16x32_bf16(al1, bh, acc1[1], 0, 0, 0);
            acc1[2] = __builtin_amdgcn_mfma_f32_16x16x32_bf16(ah2, bh, acc1[2], 0, 0, 0);
            acc1[2] = __builtin_amdgcn_mfma_f32_16x16x32_bf16(ah2, bl, acc1[2], 0, 0, 0);
            acc1[2] = __builtin_amdgcn_mfma_f32_16x16x32_bf16(al2, bh, acc1[2], 0, 0, 0);
            acc1[3] = __builtin_amdgcn_mfma_f32_16x16x32_bf16(ah3, bh, acc1[3], 0, 0, 0);
            acc1[3] = __builtin_amdgcn_mfma_f32_16x16x32_bf16(ah3, bl, acc1[3], 0, 0, 0);
            acc1[3] = __builtin_amdgcn_mfma_f32_16x16x32_bf16(al3, bh, acc1[3], 0, 0, 0);
        }
    }
    __syncthreads();

    {
        int col = c2a*16 + lm;
        if (c2a < 12) {
            #pragma unroll
            for (int t = 0; t < 4; t++)
                #pragma unroll
                for (int r = 0; r < 4; r++)
                    vt_s[(t*16 + lg*4 + r)*200 + col] = f2bf(acc0[t][r]);
        } else {
            int o = col - 192;
            #pragma unroll
            for (int t = 0; t < 4; t++)
                #pragma unroll
                for (int r = 0; r < 4; r++)
                    w0_s[(t*16 + lg*4 + r)*52 + o] = acc0[t][r];
        }
    }
    if (c2b < 15) {
        int col = c2b*16 + lm;
        if (c2b < 12) {
            #pragma unroll
            for (int t = 0; t < 4; t++)
                #pragma unroll
                for (int r = 0; r < 4; r++)
                    vt_s[(t*16 + lg*4 + r)*200 + col] = f2bf(acc1[t][r]);
        } else {
            int o = col - 192;
            #pragma unroll
            for (int t = 0; t < 4; t++)
                #pragma unroll
                for (int r = 0; r < 4; r++)
                    w0_s[(t*16 + lg*4 + r)*52 + o] = acc1[t][r];
        }
    }
    __syncthreads();

    {
        int px = tid >> 3, c8 = tid & 7;
        #pragma unroll
        for (int j = 0; j < 3; j++) {
            int ch = c8 + 8*j;
            uint4 v = *(const uint4*)&vt_s[px*200 + ch*8];
            *(uint4*)&vtb[(long)(pbase + px)*192 + ch*8] = v;
        }
        float* dst = w0v + (long)(pbase + px)*48 + c8*6;
        const float* src = w0_s + px*52 + c8*6;
        #pragma unroll
        for (int k = 0; k < 3; k++) {
            float2 v2 = *(const float2*)&src[k*2];
            *(float2*)&dst[k*2] = v2;
        }
    }
}

// ---- topk stage 1 (MFMA Gram, packed-key bubble selection, XCD-swizzled) ----
__global__ __launch_bounds__(512, 8) void topk_mfma(const u16* hht, const u16* hlt,
                                                    const float* sqp, u32* partk) {
    __shared__ u16 ca_hi[128*64];
    __shared__ u16 ca_lo[128*64];
    __shared__ float sq_s[128];

    int tid = threadIdx.x;
    int b = (blockIdx.x & 7) * 200 + (blockIdx.x >> 3);
    int chunk = b & 7, pg = (b >> 3) & 7, win = b >> 6;
    int wi = win / 5, wj = win % 5;
    int base = wi*32*WWID + wj*32;

    #pragma unroll
    for (int r = 0; r < 2; r++) {
        int task = r*512 + tid;
        int blk = task >> 7, row = task & 127;
        int swz = (blk ^ (row & 7)) * 8;
        int ml = chunk*128 + row;
        long gp = base + (ml>>5)*WWID + (ml&31);
        *(uint4*)&ca_hi[row*64 + swz] = *(const uint4*)&hht[gp*64 + blk*8];
        *(uint4*)&ca_lo[row*64 + swz] = *(const uint4*)&hlt[gp*64 + blk*8];
    }
    if (tid < 128) {
        int ml = chunk*128 + tid;
        sq_s[tid] = sqp[base + (ml>>5)*WWID + (ml&31)];
    }
    __syncthreads();

    int w = tid >> 6, lane = tid & 63;
    int lm = lane & 15, lg = lane >> 4;

    int nl = pg*128 + w*16 + lm;
    long gpx = base + (nl>>5)*WWID + (nl&31);

    f32x4 acc[8];
    #pragma unroll
    for (int t = 0; t < 8; t++) acc[t] = (f32x4){0.f, 0.f, 0.f, 0.f};

    #pragma unroll
    for (int s = 0; s < 2; s++) {
        int lblk = 4*s + lg;
        int ko = lblk * 8;
        bf16x8 bh = *(const bf16x8*)&hht[gpx*64 + ko];
        bf16x8 bl = *(const bf16x8*)&hlt[gpx*64 + ko];
        #pragma unroll
        for (int t = 0; t < 8; t++) {
            int aoff = (t*16 + lm)*64 + (lblk ^ (lm & 7))*8;
            bf16x8 ah = *(const bf16x8*)&ca_hi[aoff];
            bf16x8 al = *(const bf16x8*)&ca_lo[aoff];
            acc[t] = __builtin_amdgcn_mfma_f32_16x16x32_bf16(ah, bh, acc[t], 0, 0, 0);
            acc[t] = __builtin_amdgcn_mfma_f32_16x16x32_bf16(ah, bl, acc[t], 0, 0, 0);
            acc[t] = __builtin_amdgcn_mfma_f32_16x16x32_bf16(al, bh, acc[t], 0, 0, 0);
        }
    }

    int rn = nl >> 5, cn = nl & 31;
    int rowok[8], colok[8];
    #pragma unroll
    for (int t = 0; t < 8; t++) {
        int rm = chunk*4 + (t >> 1);
        int dr = rn - rm; dr = dr < 0 ? -dr : dr;
        rowok[t] = (dr <= 1);
    }
    #pragma unroll
    for (int j = 0; j < 8; j++) {
        int cm = (j >> 2)*16 + lg*4 + (j & 3);
        int dc = cn - cm; dc = dc < 0 ? -dc : dc;
        colok[j] = (dc <= 1);
    }

    u32 k8[8];
    #pragma unroll
    for (int s = 0; s < 8; s++) k8[s] = 0xFFFFFFFFu;

    #pragma unroll
    for (int t = 0; t < 8; t++) {
        #pragma unroll
        for (int r = 0; r < 4; r++) {
            int cl = t*16 + lg*4 + r;
            int ml = chunk*128 + cl;
            float d = fmaf(-2.0f, acc[t][r], sq_s[cl]);
            u32 u = __float_as_uint(d);
            u32 key = u ^ (0x80000000u | (u32)((int)u >> 31));
            key = (key & 0xFFFFFC00u) | (u32)ml;
            bool bad = rowok[t] && colok[(t & 1)*4 + r];
            key = bad ? 0xFFFFFFFFu : key;
            #pragma unroll
            for (int s = 0; s < 8; s++) {
                u32 lo = min(k8[s], key);
                u32 hi = max(k8[s], key);
                k8[s] = lo; key = hi;
            }
        }
    }

    #pragma unroll
    for (int st = 0; st < 2; st++) {
        int mk = (st == 0) ? 16 : 32;
        u32 o[8];
        #pragma unroll
        for (int s = 0; s < 8; s++) o[s] = (u32)__shfl_xor((int)k8[s], mk, 64);
        u32 c0 = min(k8[0], o[7]);
        u32 c1 = min(k8[1], o[6]);
        u32 c2 = min(k8[2], o[5]);
        u32 c3 = min(k8[3], o[4]);
        u32 c4 = min(k8[4], o[3]);
        u32 c5 = min(k8[5], o[2]);
        u32 c6 = min(k8[6], o[1]);
        u32 c7 = min(k8[7], o[0]);
        u32 a, bb;
        a = min(c0,c4); bb = max(c0,c4); c0 = a; c4 = bb;
        a = min(c1,c5); bb = max(c1,c5); c1 = a; c5 = bb;
        a = min(c2,c6); bb = max(c2,c6); c2 = a; c6 = bb;
        a = min(c3,c7); bb = max(c3,c7); c3 = a; c7 = bb;
        a = min(c0,c2); bb = max(c0,c2); c0 = a; c2 = bb;
        a = min(c1,c3); bb = max(c1,c3); c1 = a; c3 = bb;
        a = min(c4,c6); bb = max(c4,c6); c4 = a; c6 = bb;
        a = min(c5,c7); bb = max(c5,c7); c5 = a; c7 = bb;
        a = min(c0,c1); bb = max(c0,c1); c0 = a; c1 = bb;
        a = min(c2,c3); bb = max(c2,c3); c2 = a; c3 = bb;
        a = min(c4,c5); bb = max(c4,c5); c4 = a; c5 = bb;
        a = min(c6,c7); bb = max(c6,c7); c6 = a; c7 = bb;
        k8[0]=c0; k8[1]=c1; k8[2]=c2; k8[3]=c3; k8[4]=c4; k8[5]=c5; k8[6]=c6; k8[7]=c7;
    }

    {
        int n = base + (nl >> 5)*WWID + (nl & 31);
        u32 v0, v1;
        if      (lg == 0) { v0 = k8[0]; v1 = k8[1]; }
        else if (lg == 1) { v0 = k8[2]; v1 = k8[3]; }
        else if (lg == 2) { v0 = k8[4]; v1 = k8[5]; }
        else              { v0 = k8[6]; v1 = k8[7]; }
        u32* pk = partk + (long)chunk*8*NPIX + (long)(2*lg)*NPIX + n;
        pk[0]    = v0;
        pk[NPIX] = v1;
    }
}

// ---- ecc fused with wl: merge + ECC phases + Ubar in LDS + in-kernel WL MFMA ----
__global__ __launch_bounds__(128, 4) void ecc_kernel(const float* ws, const u32* partk,
                                                     const u16* vtb, float* outp) {
    const float* b0f = ws + OFF_B0;
    const float* bkf = ws + OFF_BK;
    const float* wkt = ws + OFF_WKT;
    const float* w0v = ws + OFF_W0V;
    const float* sqp = ws + OFF_SQP;
    const u16*   wlh = (const u16*)(ws + OFF_WLH);
    const u16*   wll = (const u16*)(ws + OFF_WLL);

    __shared__ u16 th_s[128][50];
    __shared__ __align__(16) u16 ub_s[16*200];

    int tid = threadIdx.x;
    int sb = (blockIdx.x & 7) * 200 + (blockIdx.x >> 3);
    int pix = tid >> 3, sh = tid & 7;
    int n = sb * 16 + pix;

    u32 k8[8];
    {
        const u32* pk = partk + (long)sh*8*NPIX + n;
        #pragma unroll
        for (int s = 0; s < 8; s++) k8[s] = pk[(long)s*NPIX];
    }
    #pragma unroll
    for (int st = 0; st < 3; st++) {
        int mk = 1 << st;
        u32 o[8];
        #pragma unroll
        for (int s = 0; s < 8; s++) o[s] = (u32)__shfl_xor((int)k8[s], mk, 64);
        u32 c0 = min(k8[0], o[7]);
        u32 c1 = min(k8[1], o[6]);
        u32 c2 = min(k8[2], o[5]);
        u32 c3 = min(k8[3], o[4]);
        u32 c4 = min(k8[4], o[3]);
        u32 c5 = min(k8[5], o[2]);
        u32 c6 = min(k8[6], o[1]);
        u32 c7 = min(k8[7], o[0]);
        u32 a, bb;
        a = min(c0,c4); bb = max(c0,c4); c0 = a; c4 = bb;
        a = min(c1,c5); bb = max(c1,c5); c1 = a; c5 = bb;
        a = min(c2,c6); bb = max(c2,c6); c2 = a; c6 = bb;
        a = min(c3,c7); bb = max(c3,c7); c3 = a; c7 = bb;
        a = min(c0,c2); bb = max(c0,c2); c0 = a; c2 = bb;
        a = min(c1,c3); bb = max(c1,c3); c1 = a; c3 = bb;
        a = min(c4,c6); bb = max(c4,c6); c4 = a; c6 = bb;
        a = min(c5,c7); bb = max(c5,c7); c5 = a; c7 = bb;
        a = min(c0,c1); bb = max(c0,c1); c0 = a; c1 = bb;
        a = min(c2,c3); bb = max(c2,c3); c2 = a; c3 = bb;
        a = min(c4,c5); bb = max(c4,c5); c4 = a; c5 = bb;
        a = min(c6,c7); bb = max(c6,c7); c6 = a; c7 = bb;
        k8[0]=c0; k8[1]=c1; k8[2]=c2; k8[3]=c3; k8[4]=c4; k8[5]=c5; k8[6]=c6; k8[7]=c7;
    }
    u32 key;
    {
        u32 m0 = (sh & 1) ? k8[1] : k8[0];
        u32 m1 = (sh & 1) ? k8[3] : k8[2];
        u32 m2 = (sh & 1) ? k8[5] : k8[4];
        u32 m3 = (sh & 1) ? k8[7] : k8[6];
        u32 n0 = (sh & 2) ? m1 : m0;
        u32 n1 = (sh & 2) ? m3 : m2;
        key = (sh & 4) ? n1 : n0;
    }
    int ml = (int)(key & 1023u);
    u32 uf = key & 0xFFFFFC00u;
    u32 uu = (uf & 0x80000000u) ? (uf ^ 0x80000000u) : ~uf;
    float d = __uint_as_float(uu);
    int y = n / WWID, x = n % WWID;
    int wy = (y >> 5) << 5, wx = (x >> 5) << 5;
    int m = (wy + (ml >> 5)) * WWID + (wx + (ml & 31));
    float gamma = expf(-(d + sqp[n]) * 0.1f);

    const u16* vrow = vtb + (long)m * 192;
    uint4 vv[8];
    #pragma unroll
    for (int jj = 0; jj < 8; jj++) vv[jj] = *(const uint4*)&vrow[jj*8];   // chunk0 in flight

    float th[48];
    {
        const float4* wm4 = (const float4*)(w0v + (long)m * 48);
        const float4* wn4 = (const float4*)(w0v + (long)n * 48);
        #pragma unroll
        for (int i = 0; i < 12; i++) {
            float4 a = wm4[i];
            float4 b = wn4[i];
            float x0 = a.x - b.x + b0f[4*i+0];
            float x1 = a.y - b.y + b0f[4*i+1];
            float x2 = a.z - b.z + b0f[4*i+2];
            float x3 = a.w - b.w + b0f[4*i+3];
            th[4*i+0] = (x0 >= 0.f) ? x0 : 0.01f * x0;
            th[4*i+1] = (x1 >= 0.f) ? x1 : 0.01f * x1;
            th[4*i+2] = (x2 >= 0.f) ? x2 : 0.01f * x2;
            th[4*i+3] = (x3 >= 0.f) ? x3 : 0.01f * x3;
        }
    }

    #pragma unroll
    for (int i = 0; i < 24; i++) {
        ushort2 pr;
        pr.x = f2bf(th[2*i]);
        pr.y = f2bf(th[2*i+1]);
        *(ushort2*)&th_s[tid][2*i] = pr;
    }

    float kap[12];
    #pragma unroll
    for (int r = 0; r < 12; r++) kap[r] = bkf[r];
    #pragma unroll
    for (int c = 0; c < 48; c++) {
        float t = th[c];
        const float* wkc = wkt + c*12;
        #pragma unroll
        for (int r = 0; r < 12; r++) kap[r] = fmaf(wkc[r], t, kap[r]);
    }

    float sr[12];
    #pragma unroll
    for (int r = 0; r < 12; r++) sr[r] = 0.f;
    #pragma unroll
    for (int ch = 0; ch < 3; ch++) {
        if (ch > 0) {
            #pragma unroll
            for (int jj = 0; jj < 8; jj++) vv[jj] = *(const uint4*)&vrow[(ch*8 + jj)*8];
        }
        #pragma unroll
        for (int jj = 0; jj < 8; jj++) {
            int j = ch*8 + jj;
            uint4 v4 = vv[jj];
            #pragma unroll
            for (int half = 0; half < 2; half++) {
                int cp = 2*j + half;
                u32 w0_ = half ? v4.z : v4.x;
                u32 w1_ = half ? v4.w : v4.y;
                float vx = bf2f((u16)(w0_ & 0xffff));
                float vy = bf2f((u16)(w0_ >> 16));
                float vz = bf2f((u16)(w1_ & 0xffff));
                float vw = bf2f((u16)(w1_ >> 16));
                int i1 = (cp + 1 < 48) ? cp + 1 : cp - 47;
                int i2 = (cp + 2 < 48) ? cp + 2 : cp - 46;
                float t0 = th[cp], t1 = th[i1], t2 = th[i2];
                sr[0] = fmaf(t0, vx, sr[0]); sr[1]  = fmaf(t1, vx, sr[1]);  sr[2]  = fmaf(t2, vx, sr[2]);
                sr[3] = fmaf(t0, vy, sr[3]); sr[4]  = fmaf(t1, vy, sr[4]);  sr[5]  = fmaf(t2, vy, sr[5]);
                sr[6] = fmaf(t0, vz, sr[6]); sr[7]  = fmaf(t1, vz, sr[7]);  sr[8]  = fmaf(t2, vz, sr[8]);
                sr[9] = fmaf(t0, vw, sr[9]); sr[10] = fmaf(t1, vw, sr[10]); sr[11] = fmaf(t2, vw, sr[11]);
            }
        }
    }

    float tmp[12];
    #pragma unroll
    for (int r = 0; r < 12; r++) tmp[r] = kap[r] * sr[r];

    __syncthreads();

    float acc0[6], acc1[6], acc2[6], acc3[6];
    #pragma unroll
    for (int j = 0; j < 6; j++) { acc0[j] = 0.f; acc1[j] = 0.f; acc2[j] = 0.f; acc3[j] = 0.f; }
    #pragma unroll 1
    for (int e = 0; e < 8; e++) {
        int srcl = (tid & 56) + e;
        int row  = (tid & 120) + e;
        float tm[12];
        #pragma unroll
        for (int r = 0; r < 12; r++) tm[r] = __shfl(tmp[r], srcl, 64);
        float ge = __shfl(gamma, srcl, 64);
        #pragma unroll
        for (int j = 0; j < 6; j++) {
            int cp = sh + 8*j;
            int i1 = (cp + 1 < 48) ? cp + 1 : cp - 47;
            int i2 = (cp + 2 < 48) ? cp + 2 : cp - 46;
            float t0 = bf2f(th_s[row][cp]);
            float t1 = bf2f(th_s[row][i1]);
            float t2 = bf2f(th_s[row][i2]);
            float u0 = tm[0]*t0 + tm[1]*t1 + tm[2]*t2;
            float u1 = tm[3]*t0 + tm[4]*t1 + tm[5]*t2;
            float u2 = tm[6]*t0 + tm[7]*t1 + tm[8]*t2;
            float u3 = tm[9]*t0 + tm[10]*t1 + tm[11]*t2;
            acc0[j] = fmaf(ge, u0, acc0[j]);
            acc1[j] = fmaf(ge, u1, acc1[j]);
            acc2[j] = fmaf(ge, u2, acc2[j]);
            acc3[j] = fmaf(ge, u3, acc3[j]);
        }
    }
    // Ubar -> LDS (bf16, identical rounding to the old global path)
    {
        u16* ub = &ub_s[pix*200];
        #pragma unroll
        for (int j = 0; j < 6; j++) {
            int cp = sh + 8*j;
            ushort4 st;
            st.x = f2bf(acc0[j]); st.y = f2bf(acc1[j]);
            st.z = f2bf(acc2[j]); st.w = f2bf(acc3[j]);
            *(ushort4*)&ub[cp*4] = st;
        }
    }
    __syncthreads();

    // in-kernel WL MFMA: out[48 x 16] = WL'[48 x 192] . Ubar^T (wave0: cols 0..31, wave1: 32..47)
    {
        int w2 = tid >> 6;
        int lane = tid & 63;
        int lm = lane & 15, lg = lane >> 4;
        int nb = sb * 16;
        if (w2 == 0) {
            f32x4 a0 = (f32x4){0.f,0.f,0.f,0.f};
            f32x4 a1 = (f32x4){0.f,0.f,0.f,0.f};
            #pragma unroll
            for (int ks = 0; ks < 6; ks++) {
                bf16x8 a = *(const bf16x8*)&ub_s[lm*200 + ks*32 + lg*8];
                bf16x8 bh0 = *(const bf16x8*)&wlh[( 0 + lm)*192 + ks*32 + lg*8];
                bf16x8 bl0 = *(const bf16x8*)&wll[( 0 + lm)*192 + ks*32 + lg*8];
                bf16x8 bh1 = *(const bf16x8*)&wlh[(16 + lm)*192 + ks*32 + lg*8];
                bf16x8 bl1 = *(const bf16x8*)&wll[(16 + lm)*192 + ks*32 + lg*8];
                a0 = __builtin_amdgcn_mfma_f32_16x16x32_bf16(a, bh0, a0, 0, 0, 0);
                a0 = __builtin_amdgcn_mfma_f32_16x16x32_bf16(a, bl0, a0, 0, 0, 0);
                a1 = __builtin_amdgcn_mfma_f32_16x16x32_bf16(a, bh1, a1, 0, 0, 0);
                a1 = __builtin_amdgcn_mfma_f32_16x16x32_bf16(a, bl1, a1, 0, 0, 0);
            }
            #pragma unroll
            for (int r = 0; r < 4; r++) {
                int px = lg*4 + r;
                outp[(long)( 0 + lm)*NPIX + nb + px] = 0.0625f * a0[r];
                outp[(long)(16 + lm)*NPIX + nb + px] = 0.0625f * a1[r];
            }
        } else {
            f32x4 a2 = (f32x4){0.f,0.f,0.f,0.f};
            #pragma unroll
            for (int ks = 0; ks < 6; ks++) {
                bf16x8 a = *(const bf16x8*)&ub_s[lm*200 + ks*32 + lg*8];
                bf16x8 bh2 = *(const bf16x8*)&wlh[(32 + lm)*192 + ks*32 + lg*8];
                bf16x8 bl2 = *(const bf16x8*)&wll[(32 + lm)*192 + ks*32 + lg*8];
                a2 = __builtin_amdgcn_mfma_f32_16x16x32_bf16(a, bh2, a2, 0, 0, 0);
                a2 = __builtin_amdgcn_mfma_f32_16x16x32_bf16(a, bl2, a2, 0, 0, 0);
            }
            #pragma unroll
            for (int r = 0; r < 4; r++) {
                int px = lg*4 + r;
                outp[(long)(32 + lm)*NPIX + nb + px] = 0.0625f * a2[r];
            }
        }
    }
}

// ---- conv 3x3 (reflect pad), OCH=4/thread, XCD-chunked swizzle, adds 0.5*hL + bias ----
#define OCH 4
__global__ __launch_bounds__(320) void conv_kernel(const float* h, const float* wc,
                                                   const float* bias, float* outp) {
    int sb = (blockIdx.x & 7) * 120 + (blockIdx.x >> 3);
    int og = sb % 12;
    int yp = sb / 12;
    int t  = threadIdx.x;
    int ty = t / 160;
    int x  = t % 160;
    int y  = yp * 2 + ty;

    int idx9[9];
    #pragma unroll
    for (int dy = 0; dy < 3; dy++) {
        int yy = y + dy - 1;
        yy = yy < 0 ? -yy : (yy >= HH ? 2*HH - 2 - yy : yy);
        #pragma unroll
        for (int dx = 0; dx < 3; dx++) {
            int xx = x + dx - 1;
            xx = xx < 0 ? -xx : (xx >= WWID ? 2*WWID - 2 - xx : xx);
            idx9[dy*3 + dx] = yy * WWID + xx;
        }
    }

    float acc[OCH];
    #pragma unroll
    for (int oi = 0; oi < OCH; oi++) acc[oi] = 0.f;

    const float* wbase = wc + og * OCH * 432;
    for (int c = 0; c < 48; c++) {
        float v[9];
        #pragma unroll
        for (int k = 0; k < 9; k++) v[k] = h[c*NPIX + idx9[k]];
        #pragma unroll
        for (int oi = 0; oi < OCH; oi++) {
            const float* w9 = wbase + oi*432 + c*9;
            float a = acc[oi];
            a = fmaf(v[0], w9[0], a);
            a = fmaf(v[1], w9[1], a);
            a = fmaf(v[2], w9[2], a);
            a = fmaf(v[3], w9[3], a);
            a = fmaf(v[4], w9[4], a);
            a = fmaf(v[5], w9[5], a);
            a = fmaf(v[6], w9[6], a);
            a = fmaf(v[7], w9[7], a);
            a = fmaf(v[8], w9[8], a);
            acc[oi] = a;
        }
    }

    int p = y * WWID + x;
    #pragma unroll
    for (int oi = 0; oi < OCH; oi++) {
        int o = og * OCH + oi;
        outp[o*NPIX + p] = outp[o*NPIX + p] + 0.5f * acc[oi] + bias[o];
    }
}

extern "C" void kernel_launch(void* const* d_in, const int* in_sizes, int n_in,
                              void* d_out, int out_size, void* d_ws, size_t ws_size,
                              hipStream_t stream) {
    const float* h    = (const float*)d_in[0];
    const float* W0   = (const float*)d_in[1];
    const float* b0   = (const float*)d_in[2];
    const float* WL   = (const float*)d_in[3];
    const float* WR   = (const float*)d_in[4];
    const float* Wk   = (const float*)d_in[5];
    const float* bk   = (const float*)d_in[6];
    const float* Wc   = (const float*)d_in[7];
    const float* bias = (const float*)d_in[8];

    float* ws     = (float*)d_ws;
    float* sqp    = ws + OFF_SQP;
    float* w0v    = ws + OFF_W0V;
    u16*   vtb    = (u16*)(ws + OFF_VTB);
    u16*   hht    = (u16*)(ws + OFF_HHT);
    u16*   hlt    = (u16*)(ws + OFF_HLT);
    u32*   partk  = (u32*)(ws + OFF_PARTK);
    float* outp   = (float*)d_out;

    prep_kernel<<<dim3(16), dim3(256), 0, stream>>>(W0, b0, WL, WR, Wk, bk, ws);
    split_kernel<<<dim3(200), dim3(256), 0, stream>>>(h, sqp, hht, hlt);
    topk_mfma<<<dim3(1600), dim3(512), 0, stream>>>(hht, hlt, sqp, partk);
    pixvt_mfma<<<dim3(400), dim3(512), 0, stream>>>(hht, hlt, ws, w0v, vtb);
    ecc_kernel<<<dim3(1600), dim3(128), 0, stream>>>(ws, partk, vtb, outp);
    conv_kernel<<<dim3(960), dim3(320), 0, stream>>>(h, Wc, bias, outp);
}